// Round 1
// baseline (669.973 us; speedup 1.0000x reference)
//
#include <hip/hip_runtime.h>
#include <hip/hip_bf16.h>

typedef float  f32x4  __attribute__((ext_vector_type(4)));
typedef __bf16 bf16x8 __attribute__((ext_vector_type(8)));
typedef __bf16 bf16x4 __attribute__((ext_vector_type(4)));

#define N_TOK 8192
#define D_DIM 4096
#define O_DIM 4096
#define ER    128
#define KCAT  4224   // D_DIM + ER
#define BAUX_ROWS 160  // 128 h + 8 gate + 1 thr + 23 zero pad
#define NT_MAIN 132    // KCAT / 32

// async global->LDS, 16B per lane. LDS dest must be lane-linear (wave base + lane*16).
__device__ __forceinline__ void gl_lds16(const void* g, void* l) {
  __builtin_amdgcn_global_load_lds(
      (const __attribute__((address_space(1))) void*)g,
      (__attribute__((address_space(3))) void*)l, 16, 0, 0);
}

// ---------------- k1: flat convert, shift/mask indexing only ----------------
// chunk = 8 elements. Ranges:
//   [0, 4194304)            x -> xcat[:, 0:4096] bf16        row=id>>9 ch=id&511
//   [4194304, 6291456)      Wb -> Wcat[:, 0:4096]            row=>>9  ch=&511
//   [6291456, 6356992)      Bw -> Wcat[:, 4096:4224]         o=>>4    ch=&15
//   [6356992, 6438912)      Aw/Wg/Wthr/0 -> Baux[160][4096]  row=>>9  ch=&511
__global__ __launch_bounds__(256) void convert_kernel(
    const float* __restrict__ x,  const float* __restrict__ Wb,
    const float* __restrict__ Bw, const float* __restrict__ Aw,
    const float* __restrict__ Wg, const float* __restrict__ Wthr,
    __bf16* __restrict__ xcat, __bf16* __restrict__ Wcat,
    __bf16* __restrict__ Baux)
{
  const int id = blockIdx.x * 256 + threadIdx.x;
  const float* src;
  __bf16* dst;
  if (id < 4194304) {
    int row = id >> 9, ch = id & 511;
    src = x + ((size_t)row << 12) + ch * 8;
    dst = xcat + (size_t)row * KCAT + ch * 8;
  } else if (id < 6291456) {
    int i2 = id - 4194304;
    int row = i2 >> 9, ch = i2 & 511;
    src = Wb + ((size_t)row << 12) + ch * 8;
    dst = Wcat + (size_t)row * KCAT + ch * 8;
  } else if (id < 6356992) {
    int i2 = id - 6291456;
    int o = i2 >> 4, ch = i2 & 15;          // ch: 16 chunks of the 128-wide tail
    int e = ch >> 1, r0 = (ch & 1) * 8;
    src = Bw + (((size_t)e << 12) + o) * 16 + r0;   // 8 contiguous r values
    dst = Wcat + (size_t)o * KCAT + D_DIM + ch * 8;
  } else {
    int i2 = id - 6356992;
    int row = i2 >> 9, ch = i2 & 511;       // row 0..159
    dst = Baux + ((size_t)row << 12) + ch * 8;
    if (row < 128)       src = Aw + ((size_t)row << 12) + ch * 8;
    else if (row < 136)  src = Wg + ((size_t)(row - 128) << 12) + ch * 8;
    else if (row == 136) src = Wthr + ch * 8;
    else {
      bf16x8 z = {};
      *(bf16x8*)dst = z;
      return;
    }
  }
  f32x4 a = *(const f32x4*)src;
  f32x4 b = *(const f32x4*)(src + 4);
  bf16x8 v = { (__bf16)a[0], (__bf16)a[1], (__bf16)a[2], (__bf16)a[3],
               (__bf16)b[0], (__bf16)b[1], (__bf16)b[2], (__bf16)b[3] };
  *(bf16x8*)dst = v;
}

// ---------------- k2: aux GEMM -- h[128] + gate logits[9] in one MFMA pass ----------------
// out pbuf[kc][N][160] fp32 partials; grid (64, KC); K chunk = 4096/KC
__global__ __launch_bounds__(256) void gemm_aux(
    const __bf16* __restrict__ A,    // xcat (cols 0..4095)
    const __bf16* __restrict__ Bm,   // Baux [160][4096]
    float* __restrict__ pbuf, int kchunk)
{
  __shared__ __bf16 As[128 * 64];
  __shared__ __bf16 Bs[BAUX_ROWS * 64];
  const int tid  = threadIdx.x;
  const int lane = tid & 63;
  const int wave = tid >> 6;
  const int wm = wave >> 1, wn = wave & 1;   // wave tile: 64 rows x 80 cols
  const int quad = lane >> 4, m16 = lane & 15;
  const int bm = blockIdx.x;   // 0..63 token tiles
  const int kc = blockIdx.y;

  f32x4 acc[4][5] = {};

  for (int k0 = kc * kchunk; k0 < (kc + 1) * kchunk; k0 += 64) {
#pragma unroll
    for (int i = 0; i < 4; ++i) {
      int c = i * 256 + tid;
      int row = c >> 3;
      int gk = (c & 7) ^ (row & 7);
      gl_lds16(A + (size_t)(bm * 128 + row) * KCAT + k0 + gk * 8, As + c * 8);
    }
#pragma unroll
    for (int i = 0; i < 5; ++i) {
      int c = i * 256 + tid;
      int row = c >> 3;                      // 0..159
      int gk = (c & 7) ^ (row & 7);
      gl_lds16(Bm + ((size_t)row << 12) + k0 + gk * 8, Bs + c * 8);
    }
    __syncthreads();
#pragma unroll
    for (int kk = 0; kk < 64; kk += 32) {
      bf16x8 af[4], bfr[5];
#pragma unroll
      for (int i = 0; i < 4; ++i) {
        int rr = wm * 64 + i * 16 + m16;
        int ck = (kk >> 3) + quad;
        af[i] = *(const bf16x8*)(As + rr * 64 + ((ck ^ (rr & 7)) * 8));
      }
#pragma unroll
      for (int j = 0; j < 5; ++j) {
        int rr = wn * 80 + j * 16 + m16;
        int ck = (kk >> 3) + quad;
        bfr[j] = *(const bf16x8*)(Bs + rr * 64 + ((ck ^ (rr & 7)) * 8));
      }
#pragma unroll
      for (int i = 0; i < 4; ++i)
#pragma unroll
        for (int j = 0; j < 5; ++j)
          acc[i][j] = __builtin_amdgcn_mfma_f32_16x16x32_bf16(af[i], bfr[j], acc[i][j], 0, 0, 0);
    }
    __syncthreads();
  }

#pragma unroll
  for (int j = 0; j < 5; ++j) {
    int col = wn * 80 + j * 16 + m16;
#pragma unroll
    for (int i = 0; i < 4; ++i) {
      int row0 = bm * 128 + wm * 64 + i * 16 + quad * 4;
#pragma unroll
      for (int r = 0; r < 4; ++r)
        pbuf[((size_t)kc * N_TOK + row0 + r) * BAUX_ROWS + col] = acc[i][j][r];
    }
  }
}

// ---------------- k3: combine partials + softmax/threshold + weighted bf16 tail ----------------
// 16 tokens/block, 16 threads/token.
__global__ __launch_bounds__(256) void combine_kernel(
    const float* __restrict__ pbuf,  // [KC][8192][160]
    const float* __restrict__ bthr,
    __bf16* __restrict__ xcat, int KC)
{
  const int tid = threadIdx.x;
  const int tok = tid >> 4, l16 = tid & 15;
  const int row = blockIdx.x * 16 + tok;

  __shared__ float logits[16][9];
  __shared__ float wts[16][8];

  float h[8];
  float lg = 0.f;
#pragma unroll
  for (int i = 0; i < 8; ++i) {
    int c = i * 16 + l16;
    float s = 0.f;
    for (int kc = 0; kc < KC; ++kc)
      s += pbuf[((size_t)kc * N_TOK + row) * BAUX_ROWS + c];
    h[i] = s;
  }
  {
    int c = 128 + l16;
    for (int kc = 0; kc < KC; ++kc)
      lg += pbuf[((size_t)kc * N_TOK + row) * BAUX_ROWS + c];
    if (l16 < 9) logits[tok][l16] = lg;
  }
  __syncthreads();
  if (l16 == 0) {
    float g[9];
#pragma unroll
    for (int e = 0; e < 9; ++e) g[e] = logits[tok][e];
    float m = g[0];
#pragma unroll
    for (int e = 1; e < 8; ++e) m = fmaxf(m, g[e]);
    float p[8], s = 0.f;
#pragma unroll
    for (int e = 0; e < 8; ++e) { p[e] = expf(g[e] - m); s += p[e]; }
    float thr = 0.125f / (1.f + expf(-(g[8] + bthr[0])));
    float ws = 0.f;
#pragma unroll
    for (int e = 0; e < 8; ++e) {
      float a = p[e] / s - thr;
      a = (a >= 0.f) ? a : 0.f;
      p[e] = a; ws += a;
    }
    if (ws == 0.f) ws = 1.f;
    float inv = 2.0f / ws;                    // fold SCALING=2 here
#pragma unroll
    for (int e = 0; e < 8; ++e) wts[tok][e] = p[e] * inv;
  }
  __syncthreads();
#pragma unroll
  for (int i = 0; i < 8; ++i) {
    int c = i * 16 + l16;
    xcat[(size_t)row * KCAT + D_DIM + c] = (__bf16)(h[i] * wts[tok][c >> 4]);
  }
}

// ---------------- k4: out = xcat @ Wcat^T + bias ----------------
// 256x256 tile, BK=32, 8 waves (2M x 4N), ring-4 LDS (128 KiB), depth-2 prefetch,
// counted vmcnt(4) across raw s_barrier (T3+T4), setprio around MFMA (T5),
// XCD-aware block swizzle (T1), conflict-free add-rotate LDS swizzle (T2-equivalent):
//   stored chunk p = (ck + (row>>1)) & 3, applied on the GLOBAL source (linear LDS dest)
//   and inverted on the ds_read address -> 2 lanes per 16B window per quarter-wave = free.
// Ring safety: slot s is rewritten (stage of tile t+2 at iter t) two barriers after its
// last ds_read (iter t-2); vmcnt(4) at end of iter t guarantees tile t+1's 4 loads landed
// while tile t+2's 4 remain in flight across the barrier.
__global__ __launch_bounds__(512, 2) void gemm_main(
    const __bf16* __restrict__ A,    // xcat [8192][4224]
    const __bf16* __restrict__ Bm,   // Wcat [4096][4224]
    const float* __restrict__ bias,  // [O]
    float* __restrict__ out)         // [N][O]
{
  __shared__ __bf16 As[4][256 * 32];
  __shared__ __bf16 Bs[4][256 * 32];

  const int tid  = threadIdx.x;
  const int lane = tid & 63;
  const int wave = tid >> 6;        // 0..7
  const int wm = wave >> 2;         // 0..1 : rows wm*128 .. +127
  const int wn = wave & 3;          // 0..3 : cols wn*64  .. +63
  const int quad = lane >> 4, m16 = lane & 15;

  // XCD swizzle: 512 blocks, 8 XCDs, 512%8==0 -> bijective chunked map.
  // Each XCD round works one bn (B-panel 2.2MB L2-resident) across all 32 bm.
  const int bid  = blockIdx.x;
  const int wgid = (bid & 7) * 64 + (bid >> 3);
  const int bm = wgid & 31;         // token tile 0..31
  const int bn = wgid >> 5;         // out-col tile 0..15

  // staging: per thread 2 chunks per operand per tile.
  // c = i*512+tid ; row=c>>2 ; dest chunk p=c&3 (linear) ; src chunk ck=(p-(row>>1))&3
  const int c0 = tid, c1 = 512 + tid;
  const int r0 = c0 >> 2, p0 = c0 & 3, k0 = (p0 - (r0 >> 1)) & 3;
  const int r1 = c1 >> 2, p1 = c1 & 3, k1 = (p1 - (r1 >> 1)) & 3;
  const __bf16* a0 = A  + (size_t)(bm * 256 + r0) * KCAT + k0 * 8;
  const __bf16* a1 = A  + (size_t)(bm * 256 + r1) * KCAT + k1 * 8;
  const __bf16* b0 = Bm + (size_t)(bn * 256 + r0) * KCAT + k0 * 8;
  const __bf16* b1 = Bm + (size_t)(bn * 256 + r1) * KCAT + k1 * 8;
  const int dc0 = c0 * 8, dc1 = c1 * 8;

  // fragment LDS offsets (thread-invariant): read chunk p = (quad + (row>>1)) & 3
  int aoff[8], boff[4];
#pragma unroll
  for (int i = 0; i < 8; ++i) {
    int r = wm * 128 + i * 16 + m16;
    aoff[i] = r * 32 + (((quad + (r >> 1)) & 3) * 8);
  }
#pragma unroll
  for (int j = 0; j < 4; ++j) {
    int r = wn * 64 + j * 16 + m16;
    boff[j] = r * 32 + (((quad + (r >> 1)) & 3) * 8);
  }

  f32x4 acc[8][4] = {};

  // prologue: stage tiles 0 and 1; wait tile 0 (oldest 4 of 8 loads)
  gl_lds16(a0, &As[0][dc0]);
  gl_lds16(a1, &As[0][dc1]);
  gl_lds16(b0, &Bs[0][dc0]);
  gl_lds16(b1, &Bs[0][dc1]);
  gl_lds16(a0 + 32, &As[1][dc0]);
  gl_lds16(a1 + 32, &As[1][dc1]);
  gl_lds16(b0 + 32, &Bs[1][dc0]);
  gl_lds16(b1 + 32, &Bs[1][dc1]);
  asm volatile("s_waitcnt vmcnt(4)" ::: "memory");
  __builtin_amdgcn_sched_barrier(0);
  __builtin_amdgcn_s_barrier();
  __builtin_amdgcn_sched_barrier(0);

  for (int t = 0; t < NT_MAIN; ++t) {
    // issue prefetch for tile t+2 (slot last read at iter t-2, >=2 barriers ago)
    if (t + 2 < NT_MAIN) {
      const int s2 = (t + 2) & 3;
      const int ko = (t + 2) * 32;
      gl_lds16(a0 + ko, &As[s2][dc0]);
      gl_lds16(a1 + ko, &As[s2][dc1]);
      gl_lds16(b0 + ko, &Bs[s2][dc0]);
      gl_lds16(b1 + ko, &Bs[s2][dc1]);
    }

    const __bf16* as = As[t & 3];
    const __bf16* bs = Bs[t & 3];
    bf16x8 af[8], bfr[4];
#pragma unroll
    for (int i = 0; i < 8; ++i) af[i] = *(const bf16x8*)(as + aoff[i]);
#pragma unroll
    for (int j = 0; j < 4; ++j) bfr[j] = *(const bf16x8*)(bs + boff[j]);

    __builtin_amdgcn_s_setprio(1);
#pragma unroll
    for (int i = 0; i < 8; ++i)
#pragma unroll
      for (int j = 0; j < 4; ++j)
        acc[i][j] = __builtin_amdgcn_mfma_f32_16x16x32_bf16(af[i], bfr[j], acc[i][j], 0, 0, 0);
    __builtin_amdgcn_s_setprio(0);

    // counted wait: tile t+1's 4 loads landed; tile t+2's 4 stay in flight
    if (t + 2 < NT_MAIN) {
      asm volatile("s_waitcnt vmcnt(4)" ::: "memory");
    } else {
      asm volatile("s_waitcnt vmcnt(0)" ::: "memory");
    }
    __builtin_amdgcn_sched_barrier(0);
    __builtin_amdgcn_s_barrier();
    __builtin_amdgcn_sched_barrier(0);
  }

  // epilogue: C/D layout col=lane&15, row=quad*4+reg (m89/m91-verified)
#pragma unroll
  for (int j = 0; j < 4; ++j) {
    int col = bn * 256 + wn * 64 + j * 16 + m16;
    float bv = bias[col];
#pragma unroll
    for (int i = 0; i < 8; ++i) {
      int row0 = bm * 256 + wm * 128 + i * 16 + quad * 4;
#pragma unroll
      for (int r = 0; r < 4; ++r) {
        out[(size_t)(row0 + r) * O_DIM + col] = acc[i][j][r] + bv;
      }
    }
  }
}

extern "C" void kernel_launch(void* const* d_in, const int* in_sizes, int n_in,
                              void* d_out, int out_size, void* d_ws, size_t ws_size,
                              hipStream_t stream) {
  const float* x    = (const float*)d_in[0];
  const float* Wb   = (const float*)d_in[1];
  const float* bb   = (const float*)d_in[2];
  const float* Wg   = (const float*)d_in[3];
  const float* Wthr = (const float*)d_in[4];
  const float* bthr = (const float*)d_in[5];
  const float* Aw   = (const float*)d_in[6];
  const float* Bw   = (const float*)d_in[7];
  float* out = (float*)d_out;

  // workspace layout (bytes), all 16B-aligned:
  //   xcat [8192][4224] bf16 : 69,206,016
  //   Wcat [4096][4224] bf16 : 34,603,008
  //   Baux [ 160][4096] bf16 :  1,310,720    (base = 105,119,744)
  //   pbuf [KC][8192][160] f32: KC * 5,242,880
  char* ws = (char*)d_ws;
  __bf16* xcat = (__bf16*)ws;
  __bf16* Wcat = (__bf16*)(ws + 69206016);
  __bf16* Baux = (__bf16*)(ws + 69206016 + 34603008);
  float*  pbuf = (float*)(ws + 105119744);

  // KC chosen from ws_size (constant per deployment -> graph-safe)
  int KC = 1;
  if (ws_size >= 105119744 + 4ull * 5242880) KC = 4;
  else if (ws_size >= 105119744 + 2ull * 5242880) KC = 2;

  convert_kernel<<<25152, 256, 0, stream>>>(x, Wb, Bw, Aw, Wg, Wthr, xcat, Wcat, Baux);
  dim3 agrid(64, KC);
  gemm_aux<<<agrid, 256, 0, stream>>>(xcat, Baux, pbuf, D_DIM / KC);
  combine_kernel<<<512, 256, 0, stream>>>(pbuf, bthr, xcat, KC);
  gemm_main<<<512, 512, 0, stream>>>(xcat, Wcat, bb, out);
}

// Round 2
// 605.943 us; speedup vs baseline: 1.1057x; 1.1057x over previous
//
#include <hip/hip_runtime.h>
#include <hip/hip_bf16.h>

typedef float  f32x4  __attribute__((ext_vector_type(4)));
typedef __bf16 bf16x8 __attribute__((ext_vector_type(8)));
typedef __bf16 bf16x4 __attribute__((ext_vector_type(4)));

#define N_TOK 8192
#define D_DIM 4096
#define O_DIM 4096
#define ER    128
#define KCAT  4224   // D_DIM + ER
#define BAUX_ROWS 160  // 128 h + 8 gate + 1 thr + 23 zero pad
#define NT_MAIN 132    // KCAT / 32

// async global->LDS, 16B per lane. LDS dest must be lane-linear (wave base + lane*16).
__device__ __forceinline__ void gl_lds16(const void* g, void* l) {
  __builtin_amdgcn_global_load_lds(
      (const __attribute__((address_space(1))) void*)g,
      (__attribute__((address_space(3))) void*)l, 16, 0, 0);
}

// ---------------- k1: flat convert, shift/mask indexing only ----------------
__global__ __launch_bounds__(256) void convert_kernel(
    const float* __restrict__ x,  const float* __restrict__ Wb,
    const float* __restrict__ Bw, const float* __restrict__ Aw,
    const float* __restrict__ Wg, const float* __restrict__ Wthr,
    __bf16* __restrict__ xcat, __bf16* __restrict__ Wcat,
    __bf16* __restrict__ Baux)
{
  const int id = blockIdx.x * 256 + threadIdx.x;
  const float* src;
  __bf16* dst;
  if (id < 4194304) {
    int row = id >> 9, ch = id & 511;
    src = x + ((size_t)row << 12) + ch * 8;
    dst = xcat + (size_t)row * KCAT + ch * 8;
  } else if (id < 6291456) {
    int i2 = id - 4194304;
    int row = i2 >> 9, ch = i2 & 511;
    src = Wb + ((size_t)row << 12) + ch * 8;
    dst = Wcat + (size_t)row * KCAT + ch * 8;
  } else if (id < 6356992) {
    int i2 = id - 6291456;
    int o = i2 >> 4, ch = i2 & 15;          // ch: 16 chunks of the 128-wide tail
    int e = ch >> 1, r0 = (ch & 1) * 8;
    src = Bw + (((size_t)e << 12) + o) * 16 + r0;   // 8 contiguous r values
    dst = Wcat + (size_t)o * KCAT + D_DIM + ch * 8;
  } else {
    int i2 = id - 6356992;
    int row = i2 >> 9, ch = i2 & 511;       // row 0..159
    dst = Baux + ((size_t)row << 12) + ch * 8;
    if (row < 128)       src = Aw + ((size_t)row << 12) + ch * 8;
    else if (row < 136)  src = Wg + ((size_t)(row - 128) << 12) + ch * 8;
    else if (row == 136) src = Wthr + ch * 8;
    else {
      bf16x8 z = {};
      *(bf16x8*)dst = z;
      return;
    }
  }
  f32x4 a = *(const f32x4*)src;
  f32x4 b = *(const f32x4*)(src + 4);
  bf16x8 v = { (__bf16)a[0], (__bf16)a[1], (__bf16)a[2], (__bf16)a[3],
               (__bf16)b[0], (__bf16)b[1], (__bf16)b[2], (__bf16)b[3] };
  *(bf16x8*)dst = v;
}

// ---------------- k2: aux GEMM -- h[128] + gate logits[9] in one MFMA pass ----------------
__global__ __launch_bounds__(256) void gemm_aux(
    const __bf16* __restrict__ A,    // xcat (cols 0..4095)
    const __bf16* __restrict__ Bm,   // Baux [160][4096]
    float* __restrict__ pbuf, int kchunk)
{
  __shared__ __bf16 As[128 * 64];
  __shared__ __bf16 Bs[BAUX_ROWS * 64];
  const int tid  = threadIdx.x;
  const int lane = tid & 63;
  const int wave = tid >> 6;
  const int wm = wave >> 1, wn = wave & 1;   // wave tile: 64 rows x 80 cols
  const int quad = lane >> 4, m16 = lane & 15;
  const int bm = blockIdx.x;   // 0..63 token tiles
  const int kc = blockIdx.y;

  f32x4 acc[4][5] = {};

  for (int k0 = kc * kchunk; k0 < (kc + 1) * kchunk; k0 += 64) {
#pragma unroll
    for (int i = 0; i < 4; ++i) {
      int c = i * 256 + tid;
      int row = c >> 3;
      int gk = (c & 7) ^ (row & 7);
      gl_lds16(A + (size_t)(bm * 128 + row) * KCAT + k0 + gk * 8, As + c * 8);
    }
#pragma unroll
    for (int i = 0; i < 5; ++i) {
      int c = i * 256 + tid;
      int row = c >> 3;                      // 0..159
      int gk = (c & 7) ^ (row & 7);
      gl_lds16(Bm + ((size_t)row << 12) + k0 + gk * 8, Bs + c * 8);
    }
    __syncthreads();
#pragma unroll
    for (int kk = 0; kk < 64; kk += 32) {
      bf16x8 af[4], bfr[5];
#pragma unroll
      for (int i = 0; i < 4; ++i) {
        int rr = wm * 64 + i * 16 + m16;
        int ck = (kk >> 3) + quad;
        af[i] = *(const bf16x8*)(As + rr * 64 + ((ck ^ (rr & 7)) * 8));
      }
#pragma unroll
      for (int j = 0; j < 5; ++j) {
        int rr = wn * 80 + j * 16 + m16;
        int ck = (kk >> 3) + quad;
        bfr[j] = *(const bf16x8*)(Bs + rr * 64 + ((ck ^ (rr & 7)) * 8));
      }
#pragma unroll
      for (int i = 0; i < 4; ++i)
#pragma unroll
        for (int j = 0; j < 5; ++j)
          acc[i][j] = __builtin_amdgcn_mfma_f32_16x16x32_bf16(af[i], bfr[j], acc[i][j], 0, 0, 0);
    }
    __syncthreads();
  }

#pragma unroll
  for (int j = 0; j < 5; ++j) {
    int col = wn * 80 + j * 16 + m16;
#pragma unroll
    for (int i = 0; i < 4; ++i) {
      int row0 = bm * 128 + wm * 64 + i * 16 + quad * 4;
#pragma unroll
      for (int r = 0; r < 4; ++r)
        pbuf[((size_t)kc * N_TOK + row0 + r) * BAUX_ROWS + col] = acc[i][j][r];
    }
  }
}

// ---------------- k3: combine partials + softmax/threshold + weighted bf16 tail ----------------
__global__ __launch_bounds__(256) void combine_kernel(
    const float* __restrict__ pbuf,  // [KC][8192][160]
    const float* __restrict__ bthr,
    __bf16* __restrict__ xcat, int KC)
{
  const int tid = threadIdx.x;
  const int tok = tid >> 4, l16 = tid & 15;
  const int row = blockIdx.x * 16 + tok;

  __shared__ float logits[16][9];
  __shared__ float wts[16][8];

  float h[8];
  float lg = 0.f;
#pragma unroll
  for (int i = 0; i < 8; ++i) {
    int c = i * 16 + l16;
    float s = 0.f;
    for (int kc = 0; kc < KC; ++kc)
      s += pbuf[((size_t)kc * N_TOK + row) * BAUX_ROWS + c];
    h[i] = s;
  }
  {
    int c = 128 + l16;
    for (int kc = 0; kc < KC; ++kc)
      lg += pbuf[((size_t)kc * N_TOK + row) * BAUX_ROWS + c];
    if (l16 < 9) logits[tok][l16] = lg;
  }
  __syncthreads();
  if (l16 == 0) {
    float g[9];
#pragma unroll
    for (int e = 0; e < 9; ++e) g[e] = logits[tok][e];
    float m = g[0];
#pragma unroll
    for (int e = 1; e < 8; ++e) m = fmaxf(m, g[e]);
    float p[8], s = 0.f;
#pragma unroll
    for (int e = 0; e < 8; ++e) { p[e] = expf(g[e] - m); s += p[e]; }
    float thr = 0.125f / (1.f + expf(-(g[8] + bthr[0])));
    float ws = 0.f;
#pragma unroll
    for (int e = 0; e < 8; ++e) {
      float a = p[e] / s - thr;
      a = (a >= 0.f) ? a : 0.f;
      p[e] = a; ws += a;
    }
    if (ws == 0.f) ws = 1.f;
    float inv = 2.0f / ws;                    // fold SCALING=2 here
#pragma unroll
    for (int e = 0; e < 8; ++e) wts[tok][e] = p[e] * inv;
  }
  __syncthreads();
#pragma unroll
  for (int i = 0; i < 8; ++i) {
    int c = i * 16 + l16;
    xcat[(size_t)row * KCAT + D_DIM + c] = (__bf16)(h[i] * wts[tok][c >> 4]);
  }
}

// ---------------- k4: out = xcat @ Wcat^T + bias ----------------
// 256x256 tile, BK=32, 8 waves (2M x 4N), ring-4 LDS (128 KiB), depth-2 prefetch,
// TWO phases per K-tile (m201 cadence: 16 MFMA + 4-8 ds_read + 2 stage-issues per
// phase, 2 barriers per phase, counted vmcnt once per K-tile, setprio around MFMA).
// Correctness orderings are pinned by the "memory"-clobbered vmcnt asm + ring-4's
// two-iteration WAR distance; phase barriers are schedule-shaping only.
__global__ __launch_bounds__(512, 2) void gemm_main(
    const __bf16* __restrict__ A,    // xcat [8192][4224]
    const __bf16* __restrict__ Bm,   // Wcat [4096][4224]
    const float* __restrict__ bias,  // [O]
    float* __restrict__ out)         // [N][O]
{
  __shared__ __bf16 As[4][256 * 32];
  __shared__ __bf16 Bs[4][256 * 32];

  const int tid  = threadIdx.x;
  const int lane = tid & 63;
  const int wave = tid >> 6;        // 0..7
  const int wm = wave >> 2;         // 0..1 : rows wm*128 .. +127
  const int wn = wave & 3;          // 0..3 : cols wn*64  .. +63
  const int quad = lane >> 4, m16 = lane & 15;

  // XCD swizzle: 512 blocks, 8 XCDs, 512%8==0 -> bijective chunked map.
  const int bid  = blockIdx.x;
  const int wgid = (bid & 7) * 64 + (bid >> 3);
  const int bm = wgid & 31;         // token tile 0..31
  const int bn = wgid >> 5;         // out-col tile 0..15

  // staging: per thread 2 chunks per operand per tile.
  // c = i*512+tid ; row=c>>2 ; dest chunk p=c&3 (linear) ; src chunk ck=(p-(row>>1))&3
  const int c0 = tid, c1 = 512 + tid;
  const int r0 = c0 >> 2, p0 = c0 & 3, k0 = (p0 - (r0 >> 1)) & 3;
  const int r1 = c1 >> 2, p1 = c1 & 3, k1 = (p1 - (r1 >> 1)) & 3;
  const __bf16* a0 = A  + (size_t)(bm * 256 + r0) * KCAT + k0 * 8;
  const __bf16* a1 = A  + (size_t)(bm * 256 + r1) * KCAT + k1 * 8;
  const __bf16* b0 = Bm + (size_t)(bn * 256 + r0) * KCAT + k0 * 8;
  const __bf16* b1 = Bm + (size_t)(bn * 256 + r1) * KCAT + k1 * 8;
  const int dc0 = c0 * 8, dc1 = c1 * 8;

  // fragment LDS offsets (thread-invariant): read chunk p = (quad + (row>>1)) & 3
  int aoff[8], boff[4];
#pragma unroll
  for (int i = 0; i < 8; ++i) {
    int r = wm * 128 + i * 16 + m16;
    aoff[i] = r * 32 + (((quad + (r >> 1)) & 3) * 8);
  }
#pragma unroll
  for (int j = 0; j < 4; ++j) {
    int r = wn * 64 + j * 16 + m16;
    boff[j] = r * 32 + (((quad + (r >> 1)) & 3) * 8);
  }

  f32x4 acc[8][4] = {};

  // prologue: stage tiles 0 and 1; wait tile 0 (oldest 4 of 8 loads)
  gl_lds16(a0, &As[0][dc0]);
  gl_lds16(a1, &As[0][dc1]);
  gl_lds16(b0, &Bs[0][dc0]);
  gl_lds16(b1, &Bs[0][dc1]);
  gl_lds16(a0 + 32, &As[1][dc0]);
  gl_lds16(a1 + 32, &As[1][dc1]);
  gl_lds16(b0 + 32, &Bs[1][dc0]);
  gl_lds16(b1 + 32, &Bs[1][dc1]);
  asm volatile("s_waitcnt vmcnt(4)" ::: "memory");
  __builtin_amdgcn_sched_barrier(0);
  __builtin_amdgcn_s_barrier();
  __builtin_amdgcn_sched_barrier(0);

  for (int t = 0; t < NT_MAIN; ++t) {
    const __bf16* as = As[t & 3];
    const __bf16* bs = Bs[t & 3];
    const int s2 = (t + 2) & 3;
    const int ko = (t + 2) * 32;
    const bool pf = (t + 2 < NT_MAIN);

    // ---- phase 0: ds_read A(i=0..3) + all B; issue A-stages for t+2 ----
    bf16x8 af[4], bfr[4];
#pragma unroll
    for (int i = 0; i < 4; ++i) af[i] = *(const bf16x8*)(as + aoff[i]);
#pragma unroll
    for (int j = 0; j < 4; ++j) bfr[j] = *(const bf16x8*)(bs + boff[j]);
    if (pf) {
      gl_lds16(a0 + ko, &As[s2][dc0]);
      gl_lds16(a1 + ko, &As[s2][dc1]);
    }
    __builtin_amdgcn_sched_barrier(0);
    __builtin_amdgcn_s_barrier();

    __builtin_amdgcn_s_setprio(1);
#pragma unroll
    for (int i = 0; i < 4; ++i)
#pragma unroll
      for (int j = 0; j < 4; ++j)
        acc[i][j] = __builtin_amdgcn_mfma_f32_16x16x32_bf16(af[i], bfr[j], acc[i][j], 0, 0, 0);
    __builtin_amdgcn_s_setprio(0);
    __builtin_amdgcn_sched_barrier(0);
    __builtin_amdgcn_s_barrier();

    // ---- phase 1: ds_read A(i=4..7) (B stays in regs); issue B-stages ----
    bf16x8 af2[4];
#pragma unroll
    for (int i = 0; i < 4; ++i) af2[i] = *(const bf16x8*)(as + aoff[4 + i]);
    if (pf) {
      gl_lds16(b0 + ko, &Bs[s2][dc0]);
      gl_lds16(b1 + ko, &Bs[s2][dc1]);
    }
    __builtin_amdgcn_sched_barrier(0);
    __builtin_amdgcn_s_barrier();

    __builtin_amdgcn_s_setprio(1);
#pragma unroll
    for (int i = 0; i < 4; ++i)
#pragma unroll
      for (int j = 0; j < 4; ++j)
        acc[4 + i][j] = __builtin_amdgcn_mfma_f32_16x16x32_bf16(af2[i], bfr[j], acc[4 + i][j], 0, 0, 0);
    __builtin_amdgcn_s_setprio(0);

    // counted wait: tile t+1's 4 loads landed; tile t+2's 4 stay in flight
    if (pf) {
      asm volatile("s_waitcnt vmcnt(4)" ::: "memory");
    } else {
      asm volatile("s_waitcnt vmcnt(0)" ::: "memory");
    }
    __builtin_amdgcn_sched_barrier(0);
    __builtin_amdgcn_s_barrier();
  }

  // epilogue: C/D layout col=lane&15, row=quad*4+reg (m89/m91-verified)
#pragma unroll
  for (int j = 0; j < 4; ++j) {
    int col = bn * 256 + wn * 64 + j * 16 + m16;
    float bv = bias[col];
#pragma unroll
    for (int i = 0; i < 8; ++i) {
      int row0 = bm * 256 + wm * 128 + i * 16 + quad * 4;
#pragma unroll
      for (int r = 0; r < 4; ++r) {
        out[(size_t)(row0 + r) * O_DIM + col] = acc[i][j][r] + bv;
      }
    }
  }
}

extern "C" void kernel_launch(void* const* d_in, const int* in_sizes, int n_in,
                              void* d_out, int out_size, void* d_ws, size_t ws_size,
                              hipStream_t stream) {
  const float* x    = (const float*)d_in[0];
  const float* Wb   = (const float*)d_in[1];
  const float* bb   = (const float*)d_in[2];
  const float* Wg   = (const float*)d_in[3];
  const float* Wthr = (const float*)d_in[4];
  const float* bthr = (const float*)d_in[5];
  const float* Aw   = (const float*)d_in[6];
  const float* Bw   = (const float*)d_in[7];
  float* out = (float*)d_out;

  // workspace layout (bytes), all 16B-aligned:
  //   xcat [8192][4224] bf16 : 69,206,016
  //   Wcat [4096][4224] bf16 : 34,603,008
  //   Baux [ 160][4096] bf16 :  1,310,720    (base = 105,119,744)
  //   pbuf [KC][8192][160] f32: KC * 5,242,880
  char* ws = (char*)d_ws;
  __bf16* xcat = (__bf16*)ws;
  __bf16* Wcat = (__bf16*)(ws + 69206016);
  __bf16* Baux = (__bf16*)(ws + 69206016 + 34603008);
  float*  pbuf = (float*)(ws + 105119744);

  // KC chosen from ws_size (constant per deployment -> graph-safe)
  int KC = 1;
  if (ws_size >= 105119744 + 4ull * 5242880) KC = 4;
  else if (ws_size >= 105119744 + 2ull * 5242880) KC = 2;

  convert_kernel<<<25152, 256, 0, stream>>>(x, Wb, Bw, Aw, Wg, Wthr, xcat, Wcat, Baux);
  dim3 agrid(64, KC);
  gemm_aux<<<agrid, 256, 0, stream>>>(xcat, Baux, pbuf, D_DIM / KC);
  combine_kernel<<<512, 256, 0, stream>>>(pbuf, bthr, xcat, KC);
  gemm_main<<<512, 512, 0, stream>>>(xcat, Wcat, bb, out);
}

// Round 3
// 566.924 us; speedup vs baseline: 1.1818x; 1.0688x over previous
//
#include <hip/hip_runtime.h>
#include <hip/hip_bf16.h>

typedef float  f32x4  __attribute__((ext_vector_type(4)));
typedef __bf16 bf16x8 __attribute__((ext_vector_type(8)));
typedef __bf16 bf16x4 __attribute__((ext_vector_type(4)));

#define N_TOK 8192
#define D_DIM 4096
#define O_DIM 4096
#define ER    128
#define KCAT  4224   // D_DIM + ER
#define BAUX_ROWS 160  // 128 h + 8 gate + 1 thr + 23 zero pad
#define NT_MAIN 132    // KCAT / 32

// async global->LDS, 16B per lane. LDS dest must be lane-linear (wave base + lane*16).
__device__ __forceinline__ void gl_lds16(const void* g, void* l) {
  __builtin_amdgcn_global_load_lds(
      (const __attribute__((address_space(1))) void*)g,
      (__attribute__((address_space(3))) void*)l, 16, 0, 0);
}

// ---------------- k1: flat convert, shift/mask indexing only ----------------
__global__ __launch_bounds__(256) void convert_kernel(
    const float* __restrict__ x,  const float* __restrict__ Wb,
    const float* __restrict__ Bw, const float* __restrict__ Aw,
    const float* __restrict__ Wg, const float* __restrict__ Wthr,
    __bf16* __restrict__ xcat, __bf16* __restrict__ Wcat,
    __bf16* __restrict__ Baux)
{
  const int id = blockIdx.x * 256 + threadIdx.x;
  const float* src;
  __bf16* dst;
  if (id < 4194304) {
    int row = id >> 9, ch = id & 511;
    src = x + ((size_t)row << 12) + ch * 8;
    dst = xcat + (size_t)row * KCAT + ch * 8;
  } else if (id < 6291456) {
    int i2 = id - 4194304;
    int row = i2 >> 9, ch = i2 & 511;
    src = Wb + ((size_t)row << 12) + ch * 8;
    dst = Wcat + (size_t)row * KCAT + ch * 8;
  } else if (id < 6356992) {
    int i2 = id - 6291456;
    int o = i2 >> 4, ch = i2 & 15;          // ch: 16 chunks of the 128-wide tail
    int e = ch >> 1, r0 = (ch & 1) * 8;
    src = Bw + (((size_t)e << 12) + o) * 16 + r0;   // 8 contiguous r values
    dst = Wcat + (size_t)o * KCAT + D_DIM + ch * 8;
  } else {
    int i2 = id - 6356992;
    int row = i2 >> 9, ch = i2 & 511;       // row 0..159
    dst = Baux + ((size_t)row << 12) + ch * 8;
    if (row < 128)       src = Aw + ((size_t)row << 12) + ch * 8;
    else if (row < 136)  src = Wg + ((size_t)(row - 128) << 12) + ch * 8;
    else if (row == 136) src = Wthr + ch * 8;
    else {
      bf16x8 z = {};
      *(bf16x8*)dst = z;
      return;
    }
  }
  f32x4 a = *(const f32x4*)src;
  f32x4 b = *(const f32x4*)(src + 4);
  bf16x8 v = { (__bf16)a[0], (__bf16)a[1], (__bf16)a[2], (__bf16)a[3],
               (__bf16)b[0], (__bf16)b[1], (__bf16)b[2], (__bf16)b[3] };
  *(bf16x8*)dst = v;
}

// ---------------- k2: aux GEMM -- h[128] + gate logits[9] in one MFMA pass ----------------
__global__ __launch_bounds__(256) void gemm_aux(
    const __bf16* __restrict__ A,    // xcat (cols 0..4095)
    const __bf16* __restrict__ Bm,   // Baux [160][4096]
    float* __restrict__ pbuf, int kchunk)
{
  __shared__ __bf16 As[128 * 64];
  __shared__ __bf16 Bs[BAUX_ROWS * 64];
  const int tid  = threadIdx.x;
  const int lane = tid & 63;
  const int wave = tid >> 6;
  const int wm = wave >> 1, wn = wave & 1;   // wave tile: 64 rows x 80 cols
  const int quad = lane >> 4, m16 = lane & 15;
  const int bm = blockIdx.x;   // 0..63 token tiles
  const int kc = blockIdx.y;

  f32x4 acc[4][5] = {};

  for (int k0 = kc * kchunk; k0 < (kc + 1) * kchunk; k0 += 64) {
#pragma unroll
    for (int i = 0; i < 4; ++i) {
      int c = i * 256 + tid;
      int row = c >> 3;
      int gk = (c & 7) ^ (row & 7);
      gl_lds16(A + (size_t)(bm * 128 + row) * KCAT + k0 + gk * 8, As + c * 8);
    }
#pragma unroll
    for (int i = 0; i < 5; ++i) {
      int c = i * 256 + tid;
      int row = c >> 3;                      // 0..159
      int gk = (c & 7) ^ (row & 7);
      gl_lds16(Bm + ((size_t)row << 12) + k0 + gk * 8, Bs + c * 8);
    }
    __syncthreads();
#pragma unroll
    for (int kk = 0; kk < 64; kk += 32) {
      bf16x8 af[4], bfr[5];
#pragma unroll
      for (int i = 0; i < 4; ++i) {
        int rr = wm * 64 + i * 16 + m16;
        int ck = (kk >> 3) + quad;
        af[i] = *(const bf16x8*)(As + rr * 64 + ((ck ^ (rr & 7)) * 8));
      }
#pragma unroll
      for (int j = 0; j < 5; ++j) {
        int rr = wn * 80 + j * 16 + m16;
        int ck = (kk >> 3) + quad;
        bfr[j] = *(const bf16x8*)(Bs + rr * 64 + ((ck ^ (rr & 7)) * 8));
      }
#pragma unroll
      for (int i = 0; i < 4; ++i)
#pragma unroll
        for (int j = 0; j < 5; ++j)
          acc[i][j] = __builtin_amdgcn_mfma_f32_16x16x32_bf16(af[i], bfr[j], acc[i][j], 0, 0, 0);
    }
    __syncthreads();
  }

#pragma unroll
  for (int j = 0; j < 5; ++j) {
    int col = wn * 80 + j * 16 + m16;
#pragma unroll
    for (int i = 0; i < 4; ++i) {
      int row0 = bm * 128 + wm * 64 + i * 16 + quad * 4;
#pragma unroll
      for (int r = 0; r < 4; ++r)
        pbuf[((size_t)kc * N_TOK + row0 + r) * BAUX_ROWS + col] = acc[i][j][r];
    }
  }
}

// ---------------- k3: combine partials + softmax/threshold + weighted bf16 tail ----------------
__global__ __launch_bounds__(256) void combine_kernel(
    const float* __restrict__ pbuf,  // [KC][8192][160]
    const float* __restrict__ bthr,
    __bf16* __restrict__ xcat, int KC)
{
  const int tid = threadIdx.x;
  const int tok = tid >> 4, l16 = tid & 15;
  const int row = blockIdx.x * 16 + tok;

  __shared__ float logits[16][9];
  __shared__ float wts[16][8];

  float h[8];
  float lg = 0.f;
#pragma unroll
  for (int i = 0; i < 8; ++i) {
    int c = i * 16 + l16;
    float s = 0.f;
    for (int kc = 0; kc < KC; ++kc)
      s += pbuf[((size_t)kc * N_TOK + row) * BAUX_ROWS + c];
    h[i] = s;
  }
  {
    int c = 128 + l16;
    for (int kc = 0; kc < KC; ++kc)
      lg += pbuf[((size_t)kc * N_TOK + row) * BAUX_ROWS + c];
    if (l16 < 9) logits[tok][l16] = lg;
  }
  __syncthreads();
  if (l16 == 0) {
    float g[9];
#pragma unroll
    for (int e = 0; e < 9; ++e) g[e] = logits[tok][e];
    float m = g[0];
#pragma unroll
    for (int e = 1; e < 8; ++e) m = fmaxf(m, g[e]);
    float p[8], s = 0.f;
#pragma unroll
    for (int e = 0; e < 8; ++e) { p[e] = expf(g[e] - m); s += p[e]; }
    float thr = 0.125f / (1.f + expf(-(g[8] + bthr[0])));
    float ws = 0.f;
#pragma unroll
    for (int e = 0; e < 8; ++e) {
      float a = p[e] / s - thr;
      a = (a >= 0.f) ? a : 0.f;
      p[e] = a; ws += a;
    }
    if (ws == 0.f) ws = 1.f;
    float inv = 2.0f / ws;                    // fold SCALING=2 here
#pragma unroll
    for (int e = 0; e < 8; ++e) wts[tok][e] = p[e] * inv;
  }
  __syncthreads();
#pragma unroll
  for (int i = 0; i < 8; ++i) {
    int c = i * 16 + l16;
    xcat[(size_t)row * KCAT + D_DIM + c] = (__bf16)(h[i] * wts[tok][c >> 4]);
  }
}

// ---------------- k4: out = xcat @ Wcat^T + bias ----------------
// 256x256 tile, BK=32, 8 waves (2M x 4N), ring-4 LDS (128 KiB), depth-2 prefetch.
// ONE barrier per K-tile: {12 ds_read -> 4 gl_lds(t+2) -> 32 MFMA (setprio) ->
// counted vmcnt(4) -> s_barrier}. Mid-tile barriers removed (round-2 post-mortem:
// they serialized the LDS and MFMA pipes). Correctness invariants kept:
//   RAW: tile t's stages (issued iter t-2) are vmcnt-waited at end of iter t-1,
//        then barrier'd -> visible to all waves at iter t start.
//   WAR: slot (t+2)&3 was last ds_read at iter t-2; those reads are lgkm-complete
//        before that wave's own MFMAs, hence before the end-of-(t-2) barrier ->
//        >=2-barrier distance to the restage at iter t.
//   Never drain vmcnt to 0 in steady state; drain only for the last 2 tiles.
__global__ __launch_bounds__(512, 2) void gemm_main(
    const __bf16* __restrict__ A,    // xcat [8192][4224]
    const __bf16* __restrict__ Bm,   // Wcat [4096][4224]
    const float* __restrict__ bias,  // [O]
    float* __restrict__ out)         // [N][O]
{
  __shared__ __bf16 As[4][256 * 32];
  __shared__ __bf16 Bs[4][256 * 32];

  const int tid  = threadIdx.x;
  const int lane = tid & 63;
  const int wave = tid >> 6;        // 0..7
  const int wm = wave >> 2;         // 0..1 : rows wm*128 .. +127
  const int wn = wave & 3;          // 0..3 : cols wn*64  .. +63
  const int quad = lane >> 4, m16 = lane & 15;

  // XCD swizzle: 512 blocks, 8 XCDs, 512%8==0 -> bijective chunked map.
  const int bid  = blockIdx.x;
  const int wgid = (bid & 7) * 64 + (bid >> 3);
  const int bm = wgid & 31;         // token tile 0..31
  const int bn = wgid >> 5;         // out-col tile 0..15

  // staging: per thread 2 chunks per operand per tile.
  // c = i*512+tid ; row=c>>2 ; dest chunk p=c&3 (linear) ; src chunk ck=(p-(row>>1))&3
  const int c0 = tid, c1 = 512 + tid;
  const int r0 = c0 >> 2, p0 = c0 & 3, k0 = (p0 - (r0 >> 1)) & 3;
  const int r1 = c1 >> 2, p1 = c1 & 3, k1 = (p1 - (r1 >> 1)) & 3;
  const __bf16* a0 = A  + (size_t)(bm * 256 + r0) * KCAT + k0 * 8;
  const __bf16* a1 = A  + (size_t)(bm * 256 + r1) * KCAT + k1 * 8;
  const __bf16* b0 = Bm + (size_t)(bn * 256 + r0) * KCAT + k0 * 8;
  const __bf16* b1 = Bm + (size_t)(bn * 256 + r1) * KCAT + k1 * 8;
  const int dc0 = c0 * 8, dc1 = c1 * 8;

  // fragment LDS offsets (thread-invariant): read chunk p = (quad + (row>>1)) & 3
  int aoff[8], boff[4];
#pragma unroll
  for (int i = 0; i < 8; ++i) {
    int r = wm * 128 + i * 16 + m16;
    aoff[i] = r * 32 + (((quad + (r >> 1)) & 3) * 8);
  }
#pragma unroll
  for (int j = 0; j < 4; ++j) {
    int r = wn * 64 + j * 16 + m16;
    boff[j] = r * 32 + (((quad + (r >> 1)) & 3) * 8);
  }

  f32x4 acc[8][4] = {};

  // prologue: stage tiles 0 and 1; wait tile 0 (oldest 4 of 8 loads)
  gl_lds16(a0, &As[0][dc0]);
  gl_lds16(a1, &As[0][dc1]);
  gl_lds16(b0, &Bs[0][dc0]);
  gl_lds16(b1, &Bs[0][dc1]);
  gl_lds16(a0 + 32, &As[1][dc0]);
  gl_lds16(a1 + 32, &As[1][dc1]);
  gl_lds16(b0 + 32, &Bs[1][dc0]);
  gl_lds16(b1 + 32, &Bs[1][dc1]);
  asm volatile("s_waitcnt vmcnt(4)" ::: "memory");
  __builtin_amdgcn_sched_barrier(0);
  __builtin_amdgcn_s_barrier();
  __builtin_amdgcn_sched_barrier(0);

  for (int t = 0; t < NT_MAIN; ++t) {
    const __bf16* as = As[t & 3];
    const __bf16* bs = Bs[t & 3];
    const int s2 = (t + 2) & 3;
    const int ko = (t + 2) * 32;
    const bool pf = (t + 2 < NT_MAIN);

    // fragment reads for the whole K-tile (compiler interleaves with MFMAs
    // via fine-grained lgkmcnt)
    bf16x8 af[8], bfr[4];
#pragma unroll
    for (int i = 0; i < 8; ++i) af[i] = *(const bf16x8*)(as + aoff[i]);
#pragma unroll
    for (int j = 0; j < 4; ++j) bfr[j] = *(const bf16x8*)(bs + boff[j]);

    // issue prefetch for tile t+2 (2-tile slack; lands before end of iter t+1)
    if (pf) {
      gl_lds16(a0 + ko, &As[s2][dc0]);
      gl_lds16(a1 + ko, &As[s2][dc1]);
      gl_lds16(b0 + ko, &Bs[s2][dc0]);
      gl_lds16(b1 + ko, &Bs[s2][dc1]);
    }

    __builtin_amdgcn_s_setprio(1);
#pragma unroll
    for (int i = 0; i < 8; ++i)
#pragma unroll
      for (int j = 0; j < 4; ++j)
        acc[i][j] = __builtin_amdgcn_mfma_f32_16x16x32_bf16(af[i], bfr[j], acc[i][j], 0, 0, 0);
    __builtin_amdgcn_s_setprio(0);

    // counted wait: tile t+1's 4 loads landed; tile t+2's 4 stay in flight
    if (pf) {
      asm volatile("s_waitcnt vmcnt(4)" ::: "memory");
    } else {
      asm volatile("s_waitcnt vmcnt(0)" ::: "memory");
    }
    __builtin_amdgcn_sched_barrier(0);
    __builtin_amdgcn_s_barrier();
    __builtin_amdgcn_sched_barrier(0);
  }

  // epilogue: C/D layout col=lane&15, row=quad*4+reg (m89/m91-verified)
#pragma unroll
  for (int j = 0; j < 4; ++j) {
    int col = bn * 256 + wn * 64 + j * 16 + m16;
    float bv = bias[col];
#pragma unroll
    for (int i = 0; i < 8; ++i) {
      int row0 = bm * 256 + wm * 128 + i * 16 + quad * 4;
#pragma unroll
      for (int r = 0; r < 4; ++r) {
        out[(size_t)(row0 + r) * O_DIM + col] = acc[i][j][r] + bv;
      }
    }
  }
}

extern "C" void kernel_launch(void* const* d_in, const int* in_sizes, int n_in,
                              void* d_out, int out_size, void* d_ws, size_t ws_size,
                              hipStream_t stream) {
  const float* x    = (const float*)d_in[0];
  const float* Wb   = (const float*)d_in[1];
  const float* bb   = (const float*)d_in[2];
  const float* Wg   = (const float*)d_in[3];
  const float* Wthr = (const float*)d_in[4];
  const float* bthr = (const float*)d_in[5];
  const float* Aw   = (const float*)d_in[6];
  const float* Bw   = (const float*)d_in[7];
  float* out = (float*)d_out;

  // workspace layout (bytes), all 16B-aligned:
  //   xcat [8192][4224] bf16 : 69,206,016
  //   Wcat [4096][4224] bf16 : 34,603,008
  //   Baux [ 160][4096] bf16 :  1,310,720    (base = 105,119,744)
  //   pbuf [KC][8192][160] f32: KC * 5,242,880
  char* ws = (char*)d_ws;
  __bf16* xcat = (__bf16*)ws;
  __bf16* Wcat = (__bf16*)(ws + 69206016);
  __bf16* Baux = (__bf16*)(ws + 69206016 + 34603008);
  float*  pbuf = (float*)(ws + 105119744);

  // KC chosen from ws_size (constant per deployment -> graph-safe)
  int KC = 1;
  if (ws_size >= 105119744 + 4ull * 5242880) KC = 4;
  else if (ws_size >= 105119744 + 2ull * 5242880) KC = 2;

  convert_kernel<<<25152, 256, 0, stream>>>(x, Wb, Bw, Aw, Wg, Wthr, xcat, Wcat, Baux);
  dim3 agrid(64, KC);
  gemm_aux<<<agrid, 256, 0, stream>>>(xcat, Baux, pbuf, D_DIM / KC);
  combine_kernel<<<512, 256, 0, stream>>>(pbuf, bthr, xcat, KC);
  gemm_main<<<512, 512, 0, stream>>>(xcat, Wcat, bb, out);
}